// Round 1
// baseline (182.771 us; speedup 1.0000x reference)
//
#include <hip/hip_runtime.h>

typedef short bf16x8 __attribute__((ext_vector_type(8)));
typedef float f32x4  __attribute__((ext_vector_type(4)));

__device__ __forceinline__ unsigned short f2bf(float f) {
  unsigned u = __builtin_bit_cast(unsigned, f);
  unsigned r = u + 0x7fffu + ((u >> 16) & 1u);   // RNE
  return (unsigned short)(r >> 16);
}

// X/P LDS: [64 cols][64 vals] f32, XOR-swizzle 32B slots (8-float) by (n&7)
__device__ __forceinline__ int xp_idx(int n, int h) { return n * 64 + (h ^ ((n & 7) << 3)); }
// Z LDS: [64 cols][32 k] bf16, XOR-swizzle 16B slots (8-elem) by (n&3)
__device__ __forceinline__ int z_idx(int n, int k) { return n * 32 + (k ^ ((n & 3) << 3)); }

// ---- weight permute + bf16 cast: W'[o][m*H+h] = w[o][h*40+m] ----
__global__ void permute_w_kernel(const float* __restrict__ w0,
                                 const float* __restrict__ w1,
                                 const float* __restrict__ w2,
                                 unsigned short* __restrict__ Wp) {
  int idx = blockIdx.x * 256 + threadIdx.x;
  if (idx < 204800) {                       // W0: 128 x 1600, H=40
    int o = idx / 1600, k = idx - o * 1600;
    int m = k / 40, h = k - m * 40;
    Wp[idx] = f2bf(w0[o * 1600 + h * 40 + m]);
  } else if (idx < 532480) {                // W1: 128 x 2560, H=64
    int i = idx - 204800;
    int o = i / 2560, k = i - o * 2560;
    int m = k >> 6, h = k & 63;
    Wp[idx] = f2bf(w1[o * 2560 + h * 40 + m]);
  } else if (idx < 860160) {                // W2: 128 x 2560, H=64
    int i = idx - 532480;
    int o = i / 2560, k = i - o * 2560;
    int m = k >> 6, h = k & 63;
    Wp[idx] = f2bf(w2[o * 2560 + h * 40 + m]);
  }
}

// ---- fused CIN: 64 columns (4 b x 16 d) per block, all 3 layers + head ----
__global__ __launch_bounds__(256) void cin_kernel(
    const float* __restrict__ x,
    const unsigned short* __restrict__ Wp,
    const float* __restrict__ bias0,
    const float* __restrict__ bias1,
    const float* __restrict__ bias2,
    const float* __restrict__ wl,
    float* __restrict__ out) {
  __shared__ __align__(16) float XP_s[2][64 * 64];      // [0]=X (cols x m), [1]=P (cols x h)
  __shared__ __align__(16) float XT_s[40 * 64];         // transposed X: [m][col] (bcast reads)
  __shared__ __align__(16) unsigned short Z_s[2][64 * 32];
  __shared__ float s_s[64];
  __shared__ __align__(16) float wl_s[192];

  const int tid = threadIdx.x;
  const int lane = tid & 63;
  const int wv = tid >> 6;
  const int bid = blockIdx.x;

  if (tid < 64) s_s[tid] = 0.f;
  if (tid < 192) wl_s[tid] = wl[tid];

  {  // load x for 4 b's: layout (b_l, m, d), write swizzled X + transposed XT
    const float4* xg = (const float4*)(x + (size_t)bid * 2560);
    for (int i = tid; i < 640; i += 256) {
      float4 v = xg[i];
      int d4 = (i & 3) << 2;
      int m = (i >> 2) % 40;
      int b_l = i / 160;
      int nb = b_l * 16 + d4;
      XP_s[0][xp_idx(nb + 0, m)] = v.x;
      XP_s[0][xp_idx(nb + 1, m)] = v.y;
      XP_s[0][xp_idx(nb + 2, m)] = v.z;
      XP_s[0][xp_idx(nb + 3, m)] = v.w;
      *(float4*)&XT_s[m * 64 + nb] = v;
    }
  }
  __syncthreads();

  const int zn = tid & 63;          // column this thread builds
  const int zc = tid >> 6;          // k-chunk (8 wide)
  const int obase = wv * 32;        // wave's o-range
  const int kgrp = (lane >> 4) << 3;
  const int nlo = lane & 15;
  const int orow = (lane >> 4) << 2;

  const unsigned short* W_l[3] = {Wp, Wp + 204800, Wp + 532480};
  const float* b_l[3] = {bias0, bias1, bias2};

  float sacc[4] = {0.f, 0.f, 0.f, 0.f};   // per-lane direct-part partials (waves 2,3)

  for (int l = 0; l < 3; ++l) {
    const int K = (l == 0) ? 1600 : 2560;
    const unsigned short* W = W_l[l];
    const float* Ps = XP_s[(l == 0) ? 0 : 1];
    const float* bias = b_l[l];

    f32x4 acc[2][4];
#pragma unroll
    for (int a = 0; a < 2; ++a)
#pragma unroll
      for (int b = 0; b < 4; ++b) acc[a][b] = {0.f, 0.f, 0.f, 0.f};

    const int nsteps = K >> 5;
    for (int kt = 0; kt < nsteps; ++kt) {
      const int kb = kt << 5;
      // A fragments: W'[o][kb + kgrp .. +7], 16B contiguous (issued early)
      bf16x8 afrag[2];
#pragma unroll
      for (int mr = 0; mr < 2; ++mr) {
        int o = obase + mr * 16 + nlo;
        afrag[mr] = *(const bf16x8*)(W + (size_t)o * K + kb + kgrp);
      }
      {  // build Z[k, n] = P[h,n] * X[m,n] for one 8-chunk
        int kk = kb + (zc << 3);
        int m, h0;
        if (l == 0) { m = kk / 40; h0 = kk - m * 40; }
        else        { m = kk >> 6; h0 = kk & 63; }
        float xv = XT_s[m * 64 + zn];
        const float* pb = &Ps[xp_idx(zn, h0)];
        float4 p0 = *(const float4*)pb;
        float4 p1 = *(const float4*)(pb + 4);
        bf16x8 zvv;
        zvv[0] = (short)f2bf(p0.x * xv);
        zvv[1] = (short)f2bf(p0.y * xv);
        zvv[2] = (short)f2bf(p0.z * xv);
        zvv[3] = (short)f2bf(p0.w * xv);
        zvv[4] = (short)f2bf(p1.x * xv);
        zvv[5] = (short)f2bf(p1.y * xv);
        zvv[6] = (short)f2bf(p1.z * xv);
        zvv[7] = (short)f2bf(p1.w * xv);
        *(bf16x8*)&Z_s[kt & 1][z_idx(zn, zc << 3)] = zvv;
      }
      __syncthreads();
      const unsigned short* zb = Z_s[kt & 1];
#pragma unroll
      for (int fn = 0; fn < 4; ++fn) {
        int n = fn * 16 + nlo;
        bf16x8 bfrag = *(const bf16x8*)&zb[z_idx(n, kgrp)];
        acc[0][fn] = __builtin_amdgcn_mfma_f32_16x16x32_bf16(afrag[0], bfrag, acc[0][fn], 0, 0, 0);
        acc[1][fn] = __builtin_amdgcn_mfma_f32_16x16x32_bf16(afrag[1], bfrag, acc[1][fn], 0, 0, 0);
      }
    }

    // epilogue: bias + relu; o<64 -> next P, o>=64 -> fold into direct·wl
    if (obase < 64) {
      if (l < 2) {
#pragma unroll
        for (int mr = 0; mr < 2; ++mr) {
          int o0 = obase + mr * 16 + orow;
          float4 bv = *(const float4*)&bias[o0];
#pragma unroll
          for (int fn = 0; fn < 4; ++fn) {
            f32x4 a = acc[mr][fn];
            float4 r;
            r.x = fmaxf(a[0] + bv.x, 0.f);
            r.y = fmaxf(a[1] + bv.y, 0.f);
            r.z = fmaxf(a[2] + bv.z, 0.f);
            r.w = fmaxf(a[3] + bv.w, 0.f);
            int n = fn * 16 + nlo;
            *(float4*)&XP_s[1][xp_idx(n, o0)] = r;
          }
        }
      }
    } else {
#pragma unroll
      for (int mr = 0; mr < 2; ++mr) {
        int o0 = obase + mr * 16 + orow;
        float4 bv = *(const float4*)&bias[o0];
        float4 wv4 = *(const float4*)&wl_s[l * 64 + (o0 - 64)];
#pragma unroll
        for (int fn = 0; fn < 4; ++fn) {
          f32x4 a = acc[mr][fn];
          sacc[fn] += fmaxf(a[0] + bv.x, 0.f) * wv4.x
                    + fmaxf(a[1] + bv.y, 0.f) * wv4.y
                    + fmaxf(a[2] + bv.z, 0.f) * wv4.z
                    + fmaxf(a[3] + bv.w, 0.f) * wv4.w;
        }
      }
    }
    __syncthreads();
  }

  // reduce the 4 row-groups per column, accumulate per-column scalar
#pragma unroll
  for (int fn = 0; fn < 4; ++fn) {
    float v = sacc[fn];
    v += __shfl_xor(v, 16);
    v += __shfl_xor(v, 32);
    if (wv >= 2 && lane < 16) atomicAdd(&s_s[fn * 16 + lane], v);
  }
  __syncthreads();

  if (tid < 4) {  // out[b] = sum over d of per-column scalars
    float s = 0.f;
#pragma unroll
    for (int d = 0; d < 16; ++d) s += s_s[tid * 16 + d];
    out[bid * 4 + tid] = s;
  }
}

extern "C" void kernel_launch(void* const* d_in, const int* in_sizes, int n_in,
                              void* d_out, int out_size, void* d_ws, size_t ws_size,
                              hipStream_t stream) {
  const float* x  = (const float*)d_in[0];
  const float* w0 = (const float*)d_in[1];
  const float* b0 = (const float*)d_in[2];
  const float* w1 = (const float*)d_in[3];
  const float* b1 = (const float*)d_in[4];
  const float* w2 = (const float*)d_in[5];
  const float* b2 = (const float*)d_in[6];
  const float* wl = (const float*)d_in[7];
  unsigned short* Wp = (unsigned short*)d_ws;   // 860160 bf16 = 1.72 MB

  permute_w_kernel<<<3360, 256, 0, stream>>>(w0, w1, w2, Wp);
  cin_kernel<<<512, 256, 0, stream>>>(x, Wp, b0, b1, b2, wl, (float*)d_out);
}

// Round 2
// 171.793 us; speedup vs baseline: 1.0639x; 1.0639x over previous
//
#include <hip/hip_runtime.h>
#include <hip/hip_bf16.h>

typedef short bf16x8 __attribute__((ext_vector_type(8)));
typedef float f32x4  __attribute__((ext_vector_type(4)));

__device__ __forceinline__ unsigned cvt2(float a, float b) {
  __hip_bfloat162 h = __float22bfloat162_rn(make_float2(a, b));
  unsigned u; __builtin_memcpy(&u, &h, 4); return u;
}

__device__ __forceinline__ f32x4 MFMA(bf16x8 a, bf16x8 b, f32x4 c) {
  return __builtin_amdgcn_mfma_f32_16x16x32_bf16(a, b, c, 0, 0, 0);
}

// XP: [64 cols][64 h] f32, XOR swizzle at 4-word granule -> conflict-free b128/float4
__device__ __forceinline__ int xp_idx(int n, int h) { return (n << 6) + (h ^ ((n & 7) << 2)); }
// Z: [64 cols][64 k] bf16, XOR swizzle at 8-short (16B) granule
__device__ __forceinline__ int z_idx(int n, int k) { return (n << 6) + (k ^ ((n & 7) << 3)); }

// ---- weight permute + bf16 cast, LDS transpose (coalesced read AND write) ----
// W'[o][k'] with k' = m*H + h, source w[o][h*40 + m]
__global__ __launch_bounds__(256) void permute_w_kernel(
    const float* __restrict__ w0, const float* __restrict__ w1,
    const float* __restrict__ w2, unsigned short* __restrict__ Wp) {
  __shared__ float row[2560];
  const int b = blockIdx.x;
  const float* src; unsigned short* dst; int K, H, LZ;
  if (b < 128)      { src = w0 + b * 1600;            dst = Wp + b * 1600;            K = 1600; H = 40; LZ = 1; }
  else if (b < 256) { int o = b - 128; src = w1 + o * 2560; dst = Wp + 204800 + o * 2560; K = 2560; H = 64; LZ = 0; }
  else              { int o = b - 256; src = w2 + o * 2560; dst = Wp + 532480 + o * 2560; K = 2560; H = 64; LZ = 0; }
  for (int i = threadIdx.x; i < (K >> 2); i += 256)
    *(float4*)&row[i << 2] = ((const float4*)src)[i];
  __syncthreads();
  for (int i = threadIdx.x; i < (K >> 3); i += 256) {
    const int k = i << 3;
    int m, h;
    if (LZ) { m = k / 40; h = k - m * 40; } else { m = k >> 6; h = k & 63; }
    unsigned r0 = cvt2(row[(h + 0) * 40 + m], row[(h + 1) * 40 + m]);
    unsigned r1 = cvt2(row[(h + 2) * 40 + m], row[(h + 3) * 40 + m]);
    unsigned r2 = cvt2(row[(h + 4) * 40 + m], row[(h + 5) * 40 + m]);
    unsigned r3 = cvt2(row[(h + 6) * 40 + m], row[(h + 7) * 40 + m]);
    *(uint4*)&dst[k] = make_uint4(r0, r1, r2, r3);
  }
}

// ---- fused CIN: 64 columns (4 b x 16 d) per block ----
// wave grid: (o-half) x (k-half); each wave 64o x 64n x 32k per K-step of 64
__global__ __launch_bounds__(256, 2) void cin_kernel(
    const float* __restrict__ x, const unsigned short* __restrict__ Wp,
    const float* __restrict__ bias0, const float* __restrict__ bias1,
    const float* __restrict__ bias2, const float* __restrict__ wl,
    float* __restrict__ out) {
  __shared__ __align__(16) float XP_s[64 * 64];            // X (l0), then P
  __shared__ __align__(16) float XT_s[40 * 64];            // X transposed [m][col]
  __shared__ __align__(16) unsigned short Z_s[2][64 * 64]; // Z double buffer / f32 scratch
  __shared__ __align__(16) float wl_s[192];
  __shared__ float s_s[64];

  const int tid = threadIdx.x;
  const int lane = tid & 63;
  const int wv = tid >> 6;
  const int bid = blockIdx.x;

  if (tid < 192) wl_s[tid] = wl[tid];

  {  // stage x: 4 b's, layout (b_l, m, d4)
    const float4* xg = (const float4*)(x + (size_t)bid * 2560);
    for (int i = tid; i < 640; i += 256) {
      float4 v = xg[i];
      int d4 = (i & 3) << 2;
      int m = (i >> 2) % 40;
      int b_l = i / 160;
      int nb = b_l * 16 + d4;
      XP_s[xp_idx(nb + 0, m)] = v.x;
      XP_s[xp_idx(nb + 1, m)] = v.y;
      XP_s[xp_idx(nb + 2, m)] = v.z;
      XP_s[xp_idx(nb + 3, m)] = v.w;
      *(float4*)&XT_s[m * 64 + nb] = v;
    }
  }

  // Z-build mapping: thread (zn, zc) builds k-chunks zc*8 and zc*8+32 of each 64-k step
  const int zn = tid & 63;
  const int zc = wv;
  const int sw4 = (zn & 7) << 2;
  const int xpb = zn << 6;
  const int zwoff0 = z_idx(zn, zc * 8);
  const int zwoff1 = z_idx(zn, zc * 8 + 32);

  // MFMA mapping
  const int nlo = lane & 15;
  const int kgrp = (lane >> 4) << 3;
  const int orow = (lane >> 4) << 2;
  const int swz = (nlo & 7) << 3;
  const int ohalf = wv & 1;
  const int khalf = wv >> 1;
  const int obase = ohalf << 6;
  const int zroff = (nlo << 6) + (((khalf << 5) + kgrp) ^ swz);

  f32x4 acc[4][4];
  float sacc[4] = {0.f, 0.f, 0.f, 0.f};
  const unsigned short* wb[4];

  auto set_layer_w = [&](const unsigned short* W, int K) {
#pragma unroll
    for (int mr = 0; mr < 4; ++mr)
      wb[mr] = W + (size_t)(obase + mr * 16 + nlo) * K + (khalf << 5) + kgrp;
  };
  auto zero_acc = [&]() {
#pragma unroll
    for (int mr = 0; mr < 4; ++mr)
#pragma unroll
      for (int fn = 0; fn < 4; ++fn) acc[mr][fn] = f32x4{0.f, 0.f, 0.f, 0.f};
  };
  bf16x8 A[4];
  auto aload = [&](int ks) {
    const int off = ks << 6;
#pragma unroll
    for (int mr = 0; mr < 4; ++mr) A[mr] = *(const bf16x8*)(wb[mr] + off);
  };
  auto mfma_step = [&](const unsigned short* zb) {
    const unsigned short* r = zb + zroff;
#pragma unroll
    for (int fn = 0; fn < 4; ++fn) {
      bf16x8 bf = *(const bf16x8*)(r + fn * 1024);
#pragma unroll
      for (int mr = 0; mr < 4; ++mr) acc[mr][fn] = MFMA(A[mr], bf, acc[mr][fn]);
    }
  };

  // epilogue: cross-k pair reduction through LDS scratch, then bias/relu -> P or sacc
  auto epilogue = [&](int lidx, const float* bias) {
    float* scr = ohalf ? (float*)XP_s : (float*)Z_s;
    const bool live = (lidx < 2) || (ohalf == 1);
    if (khalf == 1 && live) {
#pragma unroll
      for (int mr = 0; mr < 4; ++mr)
#pragma unroll
        for (int fn = 0; fn < 4; ++fn)
          *(f32x4*)&scr[(mr * 4 + fn) * 256 + lane * 4] = acc[mr][fn];
    }
    __syncthreads();
    if (khalf == 0 && live) {
#pragma unroll
      for (int mr = 0; mr < 4; ++mr)
#pragma unroll
        for (int fn = 0; fn < 4; ++fn)
          acc[mr][fn] += *(const f32x4*)&scr[(mr * 4 + fn) * 256 + lane * 4];
    }
    __syncthreads();  // scratch reads done before P-writes clobber XP
    if (khalf == 0 && live) {
      if (ohalf == 0) {
#pragma unroll
        for (int mr = 0; mr < 4; ++mr) {
          const int o0 = mr * 16 + orow;
          float4 bv = *(const float4*)&bias[o0];
#pragma unroll
          for (int fn = 0; fn < 4; ++fn) {
            f32x4 a = acc[mr][fn];
            float4 r;
            r.x = fmaxf(a[0] + bv.x, 0.f);
            r.y = fmaxf(a[1] + bv.y, 0.f);
            r.z = fmaxf(a[2] + bv.z, 0.f);
            r.w = fmaxf(a[3] + bv.w, 0.f);
            *(float4*)&XP_s[xp_idx(fn * 16 + nlo, o0)] = r;
          }
        }
      } else {
#pragma unroll
        for (int mr = 0; mr < 4; ++mr) {
          const int o0 = 64 + mr * 16 + orow;
          float4 bv = *(const float4*)&bias[o0];
          float4 wv4 = *(const float4*)&wl_s[lidx * 64 + (o0 - 64)];
#pragma unroll
          for (int fn = 0; fn < 4; ++fn) {
            f32x4 a = acc[mr][fn];
            sacc[fn] += fmaxf(a[0] + bv.x, 0.f) * wv4.x
                      + fmaxf(a[1] + bv.y, 0.f) * wv4.y
                      + fmaxf(a[2] + bv.z, 0.f) * wv4.z
                      + fmaxf(a[3] + bv.w, 0.f) * wv4.w;
          }
        }
      }
    }
    __syncthreads();  // new P visible for next layer
  };

  __syncthreads();  // staging done

  // ================= layer 0: P = X (LDS), pipelined pxload =================
  {
    set_layer_w(Wp, 1600);
    zero_acc();
    f32x4 P0[4], P1[4];
    float X0[2], X1[2];
    auto pxload0 = [&](int ks, f32x4 (&Pp)[4], float (&Xp)[2]) {
      const int kk0 = (ks << 6) + (zc << 3);
      const int kk1 = kk0 + 32;
      const int m0 = kk0 / 40, h0 = kk0 - m0 * 40;
      const int m1 = kk1 / 40, h1 = kk1 - m1 * 40;
      Pp[0] = *(const f32x4*)&XP_s[xpb + (h0 ^ sw4)];
      Pp[1] = *(const f32x4*)&XP_s[xpb + ((h0 + 4) ^ sw4)];
      Pp[2] = *(const f32x4*)&XP_s[xpb + (h1 ^ sw4)];
      Pp[3] = *(const f32x4*)&XP_s[xpb + ((h1 + 4) ^ sw4)];
      Xp[0] = XT_s[(m0 << 6) + zn];
      Xp[1] = XT_s[(m1 << 6) + zn];
    };
    auto zstore0 = [&](unsigned short* zb, f32x4 (&Pp)[4], float (&Xp)[2]) {
      uint4 u0, u1;
      u0.x = cvt2(Pp[0][0] * Xp[0], Pp[0][1] * Xp[0]);
      u0.y = cvt2(Pp[0][2] * Xp[0], Pp[0][3] * Xp[0]);
      u0.z = cvt2(Pp[1][0] * Xp[0], Pp[1][1] * Xp[0]);
      u0.w = cvt2(Pp[1][2] * Xp[0], Pp[1][3] * Xp[0]);
      u1.x = cvt2(Pp[2][0] * Xp[1], Pp[2][1] * Xp[1]);
      u1.y = cvt2(Pp[2][2] * Xp[1], Pp[2][3] * Xp[1]);
      u1.z = cvt2(Pp[3][0] * Xp[1], Pp[3][1] * Xp[1]);
      u1.w = cvt2(Pp[3][2] * Xp[1], Pp[3][3] * Xp[1]);
      *(uint4*)(zb + zwoff0) = u0;
      *(uint4*)(zb + zwoff1) = u1;
    };
    pxload0(0, P0, X0);
    zstore0(Z_s[0], P0, X0);
    pxload0(1, P1, X1);
    pxload0(2, P0, X0);
    __syncthreads();
    for (int kt = 0; kt < 25; kt += 2) {
      {
        aload(kt);
        if (kt + 1 < 25) zstore0(Z_s[1], P1, X1);
        if (kt + 3 < 25) pxload0(kt + 3, P1, X1);
        mfma_step(Z_s[0]);
        __syncthreads();
      }
      if (kt + 1 < 25) {
        aload(kt + 1);
        if (kt + 2 < 25) zstore0(Z_s[0], P0, X0);
        if (kt + 4 < 25) pxload0(kt + 4, P0, X0);
        mfma_step(Z_s[1]);
        __syncthreads();
      }
    }
    epilogue(0, bias0);
  }

  // ================= layers 1,2: P cached in registers =================
  for (int lidx = 1; lidx < 3; ++lidx) {
    const unsigned short* W = (lidx == 1) ? (Wp + 204800) : (Wp + 532480);
    const float* bias = (lidx == 1) ? bias1 : bias2;
    set_layer_w(W, 2560);
    zero_acc();
    // per-thread P slice: h = zc*8 + {0..7} and zc*8+32 + {0..7}, constant all steps
    f32x4 Pc[4];
    Pc[0] = *(const f32x4*)&XP_s[xpb + ((zc * 8) ^ sw4)];
    Pc[1] = *(const f32x4*)&XP_s[xpb + ((zc * 8 + 4) ^ sw4)];
    Pc[2] = *(const f32x4*)&XP_s[xpb + ((zc * 8 + 32) ^ sw4)];
    Pc[3] = *(const f32x4*)&XP_s[xpb + ((zc * 8 + 36) ^ sw4)];
    auto zstore12 = [&](unsigned short* zb, float xv) {
      uint4 u0, u1;
      u0.x = cvt2(Pc[0][0] * xv, Pc[0][1] * xv);
      u0.y = cvt2(Pc[0][2] * xv, Pc[0][3] * xv);
      u0.z = cvt2(Pc[1][0] * xv, Pc[1][1] * xv);
      u0.w = cvt2(Pc[1][2] * xv, Pc[1][3] * xv);
      u1.x = cvt2(Pc[2][0] * xv, Pc[2][1] * xv);
      u1.y = cvt2(Pc[2][2] * xv, Pc[2][3] * xv);
      u1.z = cvt2(Pc[3][0] * xv, Pc[3][1] * xv);
      u1.w = cvt2(Pc[3][2] * xv, Pc[3][3] * xv);
      *(uint4*)(zb + zwoff0) = u0;
      *(uint4*)(zb + zwoff1) = u1;
    };
    float xv0 = XT_s[zn];        // m = 0
    float xv1 = XT_s[64 + zn];   // m = 1
    zstore12(Z_s[0], xv0);
    __syncthreads();
    for (int kt = 0; kt < 40; kt += 2) {
      {
        aload(kt);
        if (kt + 1 < 40) zstore12(Z_s[1], xv1);
        if (kt + 2 < 40) xv0 = XT_s[((kt + 2) << 6) + zn];
        mfma_step(Z_s[0]);
        __syncthreads();
      }
      {
        aload(kt + 1);
        if (kt + 2 < 40) zstore12(Z_s[0], xv0);
        if (kt + 3 < 40) xv1 = XT_s[((kt + 3) << 6) + zn];
        mfma_step(Z_s[1]);
        __syncthreads();
      }
    }
    epilogue(lidx, bias);
  }

  // ================= head: wave 1 holds all direct-row partials =================
#pragma unroll
  for (int fn = 0; fn < 4; ++fn) {
    float v = sacc[fn];
    v += __shfl_xor(v, 16);
    v += __shfl_xor(v, 32);
    if (wv == 1 && lane < 16) s_s[fn * 16 + lane] = v;
  }
  __syncthreads();
  if (tid < 4) {
    float s = 0.f;
#pragma unroll
    for (int d = 0; d < 16; ++d) s += s_s[tid * 16 + d];
    out[bid * 4 + tid] = s;
  }
}

extern "C" void kernel_launch(void* const* d_in, const int* in_sizes, int n_in,
                              void* d_out, int out_size, void* d_ws, size_t ws_size,
                              hipStream_t stream) {
  const float* x  = (const float*)d_in[0];
  const float* w0 = (const float*)d_in[1];
  const float* b0 = (const float*)d_in[2];
  const float* w1 = (const float*)d_in[3];
  const float* b1 = (const float*)d_in[4];
  const float* w2 = (const float*)d_in[5];
  const float* b2 = (const float*)d_in[6];
  const float* wl = (const float*)d_in[7];
  unsigned short* Wp = (unsigned short*)d_ws;  // 860160 bf16 = 1.72 MB

  permute_w_kernel<<<384, 256, 0, stream>>>(w0, w1, w2, Wp);
  cin_kernel<<<512, 256, 0, stream>>>(x, Wp, b0, b1, b2, wl, (float*)d_out);
}